// Round 1
// baseline (1033.729 us; speedup 1.0000x reference)
//
#include <hip/hip_runtime.h>

namespace {
constexpr int NZ = 256, NX = 256, NT = 256, NR = 128, B = 4;
constexpr int ROWS = 4;                  // rows owned per block
constexpr int BPS = NZ / ROWS;           // blocks per shot = 64
constexpr float DT = 1e-3f, DH = 10.0f, OMEGA = 10.0f;
constexpr float TS = 1.0f / OMEGA;       // tau_sigma = 0.1
constexpr float CAv = 1.0f - DT / (2.0f * TS);   // 0.995
constexpr float CBv = 1.0f + DT / (2.0f * TS);   // 1.005
}

// Precompute per-cell coefficients:
//   A1 = DT/(rho*DH)                      (velocity update)
//   B2 = DT*kappa*tau/(tau_sigma*cb*DH)   (memory-variable update, div folded)
//   B3 = DT*kappa*(1+tau)/DH              (pressure update)
__global__ void coef_kernel(const float* __restrict__ vp, const float* __restrict__ rho,
                            const float* __restrict__ Q,
                            float* __restrict__ A1, float* __restrict__ B2c,
                            float* __restrict__ B3c) {
  int i = blockIdx.x * blockDim.x + threadIdx.x;
  if (i >= NZ * NX) return;
  float v = vp[i], rh = rho[i], q = Q[i];
  float kappa = rh * v * v;
  float tau = 1.0f / q;
  A1[i] = DT / (rh * DH);
  B2c[i] = DT * kappa * tau / (TS * CBv * DH);
  B3c[i] = DT * kappa * (1.0f + tau) / DH;
}

// One full time step. Each block: shot b, rows [z0, z0+ROWS).
// Reads old p (ping) + old vz (ping) with halos; computes velocities
// (incl. one redundant vz row) from old state only -> no cross-block race.
// Writes new p/vz to pong buffers; vx, r updated in place (own rows only).
// Receiver readout of the PREVIOUS step's p is done by the owner block of
// row rec_z from its LDS snapshot, before any overwrite.
__global__ __launch_bounds__(256) void step_kernel(
    const float* __restrict__ p_in, float* __restrict__ p_out,
    const float* __restrict__ vz_in, float* __restrict__ vz_out,
    float* __restrict__ vx, float* __restrict__ rmem,
    const float* __restrict__ A1, const float* __restrict__ B2c,
    const float* __restrict__ B3c,
    const float* __restrict__ wav,           // x: [B, NT, 1]
    const int* __restrict__ src_z, const int* __restrict__ src_x,
    const int* __restrict__ rec_x, const int* __restrict__ rec_z,
    float* __restrict__ out, int t)
{
  const int x  = threadIdx.x;              // column 0..255
  const int b  = blockIdx.x / BPS;         // shot
  const int zb = blockIdx.x % BPS;         // row-block within shot
  const int z0 = zb * ROWS;

  __shared__ float p_s[ROWS + 2][NX + 1];  // rows z0-1 .. z0+ROWS, col pad at 0
  __shared__ float vx_s[ROWS][NX + 1];     // vx_s[i][NX] = 0 (dxf pad)
  __shared__ float vz_s[ROWS + 1][NX];     // incl. redundant row z0+ROWS

  const size_t base = (size_t)b * NZ * NX;

  #pragma unroll
  for (int k = 0; k < ROWS + 2; ++k) {
    int z = z0 - 1 + k;
    p_s[k][x + 1] = (z >= 0 && z < NZ) ? p_in[base + (size_t)z * NX + x] : 0.0f;
  }
  if (x < ROWS + 2) p_s[x][0] = 0.0f;      // p[z][-1] ghost = 0 (dxb pad)
  if (x < ROWS)     vx_s[x][NX] = 0.0f;    // vx[z][NX] ghost = 0 (dxf pad)
  __syncthreads();

  // --- record previous step's receivers: out[t-1, r, b] = p_prev[b, rz, rec_x[r]]
  const int rz = rec_z[0];
  if (t > 0 && zb == (rz / ROWS) && x < NR) {
    int rx = rec_x[x];
    out[(size_t)(t - 1) * NR * B + (size_t)x * B + b] = p_s[rz - z0 + 1][rx + 1];
  }

  // --- velocity updates (from old p) ---
  #pragma unroll
  for (int i = 0; i < ROWS; ++i) {
    int gi = (z0 + i) * NX + x;
    float a1  = A1[gi];
    float vxn = vx[base + gi] - a1 * (p_s[i + 1][x + 1] - p_s[i + 1][x]);
    vx_s[i][x] = vxn;
    vx[base + gi] = vxn;
    float vzn = vz_in[base + gi] - a1 * (p_s[i + 1][x + 1] - p_s[i][x + 1]);
    vz_s[i][x] = vzn;
    vz_out[base + gi] = vzn;
  }
  {   // redundant vz row z0+ROWS (owned by the next block; recomputed here)
    int z = z0 + ROWS;
    if (z < NZ) {
      int gi = z * NX + x;
      vz_s[ROWS][x] = vz_in[base + gi]
                    - A1[gi] * (p_s[ROWS + 1][x + 1] - p_s[ROWS][x + 1]);
    } else {
      vz_s[ROWS][x] = 0.0f;                // vz[NZ][x] ghost = 0 (dzf pad)
    }
  }
  __syncthreads();

  // --- memory variable + pressure updates ---
  const int sz = src_z[b], sx = src_x[b];
  const float xi = wav[b * NT + t];
  constexpr float CA = CAv / CBv;

  #pragma unroll
  for (int i = 0; i < ROWS; ++i) {
    int z  = z0 + i;
    int gi = z * NX + x;
    float divr = (vx_s[i][x + 1] - vx_s[i][x]) + (vz_s[i + 1][x] - vz_s[i][x]);
    float rn = CA * rmem[base + gi] - B2c[gi] * divr;
    rmem[base + gi] = rn;
    float pn = p_s[i + 1][x + 1] - B3c[gi] * divr + DT * rn;
    if (z == sz && x == sx) pn += xi;      // source injection (owner block)
    p_out[base + gi] = pn;
  }
}

__global__ void final_readout(const float* __restrict__ p, const int* __restrict__ rec_x,
                              const int* __restrict__ rec_z, float* __restrict__ out) {
  int tid = blockIdx.x * blockDim.x + threadIdx.x;
  if (tid >= NR * B) return;
  int rr = tid / B, b = tid % B;
  int rz = rec_z[0];
  out[(size_t)(NT - 1) * NR * B + (size_t)rr * B + b] =
      p[((size_t)b * NZ + rz) * NX + rec_x[rr]];
}

extern "C" void kernel_launch(void* const* d_in, const int* in_sizes, int n_in,
                              void* d_out, int out_size, void* d_ws, size_t ws_size,
                              hipStream_t stream) {
  const float* xw   = (const float*)d_in[0];  // [B, NT, 1]
  const float* vp   = (const float*)d_in[1];  // [NZ, NX]
  const float* rho  = (const float*)d_in[2];
  const float* Q    = (const float*)d_in[3];
  const int* src_z  = (const int*)d_in[4];    // [B]
  const int* src_x  = (const int*)d_in[5];    // [B]
  const int* rec_x  = (const int*)d_in[6];    // [NR]
  const int* rec_z  = (const int*)d_in[7];    // [1]
  float* out = (float*)d_out;                 // [NT, NR, B] float32
  float* ws  = (float*)d_ws;

  const size_t S = (size_t)B * NZ * NX;       // 262144 elems per state array
  float* p0  = ws;
  float* p1  = ws + S;
  float* vz0 = ws + 2 * S;
  float* vz1 = ws + 3 * S;
  float* vx  = ws + 4 * S;
  float* rm  = ws + 5 * S;
  float* A1  = ws + 6 * S;
  float* B2c = A1 + (size_t)NZ * NX;
  float* B3c = B2c + (size_t)NZ * NX;

  hipMemsetAsync(ws, 0, 6 * S * sizeof(float), stream);   // zero state each call
  coef_kernel<<<(NZ * NX + 255) / 256, 256, 0, stream>>>(vp, rho, Q, A1, B2c, B3c);

  for (int t = 0; t < NT; ++t) {
    const float* pin  = (t & 1) ? p1 : p0;
    float* pout       = (t & 1) ? p0 : p1;
    const float* vzin = (t & 1) ? vz1 : vz0;
    float* vzout      = (t & 1) ? vz0 : vz1;
    step_kernel<<<B * BPS, 256, 0, stream>>>(pin, pout, vzin, vzout, vx, rm,
                                             A1, B2c, B3c, xw, src_z, src_x,
                                             rec_x, rec_z, out, t);
  }
  // p after step NT-1 lives in p0 (NT even)
  final_readout<<<(NR * B + 255) / 256, 256, 0, stream>>>(p0, rec_x, rec_z, out);
}